// Round 1
// baseline (430.333 us; speedup 1.0000x reference)
//
#include <hip/hip_runtime.h>

// Blockwise 8x8 2D orthonormal DCT:
//   x: (64, 1, 1024, 1024) fp32  ->  out: (64, 64, 128, 128) fp32
//   out[n][i*8+j][gi][gj] = sum_{k,l} A[i][k] * x[n][0][gi*8+k][gj*8+l] * A[j][l]
//
// Memory-bound (512 MB traffic). One thread per 8x8 tile.
// A is the FIXED orthonormal DCT-II matrix -> hard-coded fast butterfly:
// per 8-point transform: 12 add/sub + ~24 mul/fma instead of 64 FMA + LDS reads.
// No LDS, no __syncthreads, ~100 VGPRs -> high occupancy for latency hiding.

#define BS    8
#define HW    1024
#define GH    128
#define GW    128
#define NIMG  64
#define PLANE (GH * GW)

// DCT-II constants: A[i][n] = 0.5*cos((2n+1)*i*pi/16), row 0 scaled by 1/sqrt(2)
#define C_035 0.35355339059327376f   // 0.5/sqrt(2)
#define C_049 0.49039264020161522f   // 0.5*cos(1*pi/16)
#define C_046 0.46193976625564337f   // 0.5*cos(2*pi/16)
#define C_041 0.41573480615127262f   // 0.5*cos(3*pi/16)
#define C_027 0.27778511650980114f   // 0.5*cos(5*pi/16)
#define C_019 0.19134171618254492f   // 0.5*cos(6*pi/16)
#define C_009 0.09754516100806413f   // 0.5*cos(7*pi/16)

// Orthonormal 8-point DCT-II via even/odd butterfly.
// X[i] = sum_n A[i][n] * v[n]; uses A[i][7-n] = +/-A[i][n].
__device__ __forceinline__ void dct8(const float* __restrict__ v,
                                     float* __restrict__ X) {
    const float e0 = v[0] + v[7], e1 = v[1] + v[6];
    const float e2 = v[2] + v[5], e3 = v[3] + v[4];
    const float o0 = v[0] - v[7], o1 = v[1] - v[6];
    const float o2 = v[2] - v[5], o3 = v[3] - v[4];
    const float ee0 = e0 + e3, ee1 = e1 + e2;
    const float eo0 = e0 - e3, eo1 = e1 - e2;
    X[0] = C_035 * (ee0 + ee1);
    X[4] = C_035 * (ee0 - ee1);
    X[2] = C_046 * eo0 + C_019 * eo1;
    X[6] = C_019 * eo0 - C_046 * eo1;
    X[1] = C_049 * o0 + C_041 * o1 + C_027 * o2 + C_009 * o3;
    X[3] = C_041 * o0 - C_009 * o1 - C_049 * o2 - C_027 * o3;
    X[5] = C_027 * o0 - C_049 * o1 + C_009 * o2 + C_041 * o3;
    X[7] = C_009 * o0 - C_027 * o1 + C_041 * o2 - C_049 * o3;
}

__global__ __launch_bounds__(256) void dct2d_kernel(
        const float* __restrict__ x,
        const float* __restrict__ A,   // unused: matrix is hard-coded
        float* __restrict__ out) {
    (void)A;
    const int id  = blockIdx.x * 256 + threadIdx.x;   // [0, 64*128*128)
    const int n   = id >> 14;                         // / (128*128)
    const int rem = id & 16383;
    const int gi  = rem >> 7;                         // / 128
    const int gj  = rem & 127;

    const float* xp = x + (size_t)n * (HW * HW) + (size_t)(gi * BS) * HW + gj * BS;

    // Stage 1: row transforms. t[k][j] = sum_l block[k][l] * A[j][l]
    float t[8][8];
    #pragma unroll
    for (int k = 0; k < 8; ++k) {
        const float4 lo = *(const float4*)(xp + (size_t)k * HW);
        const float4 hi = *(const float4*)(xp + (size_t)k * HW + 4);
        const float v[8] = {lo.x, lo.y, lo.z, lo.w, hi.x, hi.y, hi.z, hi.w};
        dct8(v, t[k]);
    }

    // Stage 2: column transforms + store. coeff[i][j] = sum_k A[i][k] * t[k][j]
    float* op = out + (size_t)n * (64 * PLANE) + (size_t)gi * GW + gj;
    #pragma unroll
    for (int j = 0; j < 8; ++j) {
        float c[8];
        #pragma unroll
        for (int k = 0; k < 8; ++k) c[k] = t[k][j];
        float X[8];
        dct8(c, X);
        #pragma unroll
        for (int i = 0; i < 8; ++i)
            op[(size_t)(i * 8 + j) * PLANE] = X[i];   // coalesced: lane = gj
    }
}

extern "C" void kernel_launch(void* const* d_in, const int* in_sizes, int n_in,
                              void* d_out, int out_size, void* d_ws, size_t ws_size,
                              hipStream_t stream) {
    const float* x = (const float*)d_in[0];
    const float* A = (const float*)d_in[1];
    float* out     = (float*)d_out;

    const int total_threads = NIMG * GH * GW;       // 1,048,576
    const int block = 256;
    const int grid  = total_threads / block;        // 4096 (exact)
    dct2d_kernel<<<grid, block, 0, stream>>>(x, A, out);
}

// Round 2
// 427.757 us; speedup vs baseline: 1.0060x; 1.0060x over previous
//
#include <hip/hip_runtime.h>

// Blockwise 8x8 2D orthonormal DCT:
//   x: (64, 1, 1024, 1024) fp32  ->  out: (64, 64, 128, 128) fp32
//
// One thread per 8x8 tile, hard-coded DCT-II butterfly (no A loads, no matrix FMA).
// NEW vs prev round: stores go through a 16 KB LDS transpose so each wave issues
// float4 stores of 1 KB contiguous (one output-channel block region per (s,wave)),
// replacing 64 scalar dword stores per thread (was 80 outstanding VMEM ops/wave,
// near the 63-entry vmcnt queue).
//
// Block = 256 threads = 2 full gj-rows of tiles (gi0 even). Per channel ch, the
// block owns out[n][ch][gi0..gi0+1][0..127] = 256 contiguous floats.

#define BS    8
#define HW    1024
#define GH    128
#define GW    128
#define NIMG  64
#define PLANE (GH * GW)

// DCT-II constants: A[i][n] = 0.5*cos((2n+1)*i*pi/16), row 0 scaled by 1/sqrt(2)
#define C_035 0.35355339059327376f   // 0.5/sqrt(2)
#define C_049 0.49039264020161522f   // 0.5*cos(1*pi/16)
#define C_046 0.46193976625564337f   // 0.5*cos(2*pi/16)
#define C_041 0.41573480615127262f   // 0.5*cos(3*pi/16)
#define C_027 0.27778511650980114f   // 0.5*cos(5*pi/16)
#define C_019 0.19134171618254492f   // 0.5*cos(6*pi/16)
#define C_009 0.09754516100806413f   // 0.5*cos(7*pi/16)

__device__ __forceinline__ void dct8(const float* __restrict__ v,
                                     float* __restrict__ X) {
    const float e0 = v[0] + v[7], e1 = v[1] + v[6];
    const float e2 = v[2] + v[5], e3 = v[3] + v[4];
    const float o0 = v[0] - v[7], o1 = v[1] - v[6];
    const float o2 = v[2] - v[5], o3 = v[3] - v[4];
    const float ee0 = e0 + e3, ee1 = e1 + e2;
    const float eo0 = e0 - e3, eo1 = e1 - e2;
    X[0] = C_035 * (ee0 + ee1);
    X[4] = C_035 * (ee0 - ee1);
    X[2] = C_046 * eo0 + C_019 * eo1;
    X[6] = C_019 * eo0 - C_046 * eo1;
    X[1] = C_049 * o0 + C_041 * o1 + C_027 * o2 + C_009 * o3;
    X[3] = C_041 * o0 - C_009 * o1 - C_049 * o2 - C_027 * o3;
    X[5] = C_027 * o0 - C_049 * o1 + C_009 * o2 + C_041 * o3;
    X[7] = C_009 * o0 - C_027 * o1 + C_041 * o2 - C_049 * o3;
}

__global__ __launch_bounds__(256) void dct2d_kernel(
        const float* __restrict__ x,
        const float* __restrict__ A,   // unused: matrix is hard-coded
        float* __restrict__ out) {
    (void)A;
    __shared__ float lds[16 * 256];   // 16 KB: 16 channels x 256 block positions

    const int tid = threadIdx.x;
    const int id  = blockIdx.x * 256 + tid;   // [0, 64*128*128)
    const int n   = id >> 14;                 // / (128*128)
    const int rem = id & 16383;
    const int gi  = rem >> 7;                 // / 128
    const int gj  = rem & 127;
    const int gi0 = gi & ~1;                  // block's first tile-row (blocks are 2-row aligned)

    const float* xp = x + (size_t)n * (HW * HW) + (size_t)(gi * BS) * HW + gj * BS;

    // Stage 1: row transforms. t[k][j] = sum_l block[k][l] * A[j][l]
    float t[8][8];
    #pragma unroll
    for (int k = 0; k < 8; ++k) {
        const float4 lo = *(const float4*)(xp + (size_t)k * HW);
        const float4 hi = *(const float4*)(xp + (size_t)k * HW + 4);
        const float v[8] = {lo.x, lo.y, lo.z, lo.w, hi.x, hi.y, hi.z, hi.w};
        dct8(v, t[k]);
    }

    // Stage 2: column transforms. X[i][j] = sum_k A[i][k] * t[k][j]
    float X[8][8];
    #pragma unroll
    for (int j = 0; j < 8; ++j) {
        float c[8];
        #pragma unroll
        for (int k = 0; k < 8; ++k) c[k] = t[k][j];
        float col[8];
        dct8(c, col);
        #pragma unroll
        for (int i = 0; i < 8; ++i) X[i][j] = col[i];
    }

    // Stage 3: store via LDS transpose, 16 channels (2 i-rows) per round.
    // Write:  lds[ch_local][tid] = X[2r+ii][j],  ch_local = ii*8+j  (conflict-free:
    //         consecutive tid -> consecutive banks).
    // Read:   (s, wave) pair owns channel ch_local = 4s+w; lane l reads float4 at
    //         lds[ch_local*256 + 4l] and stores 1 KB contiguous per wave.
    const int w = tid >> 6;          // wave id 0..3
    const int l = tid & 63;          // lane
    float* obase = out + (size_t)n * (64 * PLANE) + (size_t)gi0 * GW;

    #pragma unroll
    for (int r = 0; r < 4; ++r) {
        if (r) __syncthreads();      // protect LDS reuse from previous round's reads
        #pragma unroll
        for (int ii = 0; ii < 2; ++ii)
            #pragma unroll
            for (int j = 0; j < 8; ++j)
                lds[(ii * 8 + j) * 256 + tid] = X[2 * r + ii][j];
        __syncthreads();
        #pragma unroll
        for (int s = 0; s < 4; ++s) {
            const int ch_local = 4 * s + w;            // 0..15
            const int ch = r * 16 + ch_local;          // 0..63
            const float4 v = *(const float4*)&lds[ch_local * 256 + 4 * l];
            *(float4*)(obase + (size_t)ch * PLANE + 4 * l) = v;
        }
    }
}

extern "C" void kernel_launch(void* const* d_in, const int* in_sizes, int n_in,
                              void* d_out, int out_size, void* d_ws, size_t ws_size,
                              hipStream_t stream) {
    const float* x = (const float*)d_in[0];
    const float* A = (const float*)d_in[1];
    float* out     = (float*)d_out;

    const int total_threads = NIMG * GH * GW;       // 1,048,576
    const int block = 256;
    const int grid  = total_threads / block;        // 4096 (exact)
    dct2d_kernel<<<grid, block, 0, stream>>>(x, A, out);
}

// Round 5
// 412.050 us; speedup vs baseline: 1.0444x; 1.0381x over previous
//
#include <hip/hip_runtime.h>

// Blockwise 8x8 2D orthonormal DCT:
//   x: (64, 1, 1024, 1024) fp32  ->  out: (64, 64, 128, 128) fp32
//
// One thread per 8x8 tile, hard-coded DCT-II butterfly. Stores via 16 KB LDS
// transpose -> 1 KB contiguous float4 store per wave per channel.
// Non-temporal (nt) hints on touch-once loads and streaming stores: 512 MB
// working set > 256 MiB Infinity Cache; avoid write-allocate/retain churn.
// NOTE: __builtin_nontemporal_* needs a clang vector type, not HIP's struct
// float4 -> use ext_vector_type(4).

#define BS    8
#define HW    1024
#define GH    128
#define GW    128
#define NIMG  64
#define PLANE (GH * GW)

typedef float f32x4 __attribute__((ext_vector_type(4)));

// DCT-II constants: A[i][n] = 0.5*cos((2n+1)*i*pi/16), row 0 scaled by 1/sqrt(2)
#define C_035 0.35355339059327376f   // 0.5/sqrt(2)
#define C_049 0.49039264020161522f   // 0.5*cos(1*pi/16)
#define C_046 0.46193976625564337f   // 0.5*cos(2*pi/16)
#define C_041 0.41573480615127262f   // 0.5*cos(3*pi/16)
#define C_027 0.27778511650980114f   // 0.5*cos(5*pi/16)
#define C_019 0.19134171618254492f   // 0.5*cos(6*pi/16)
#define C_009 0.09754516100806413f   // 0.5*cos(7*pi/16)

__device__ __forceinline__ void dct8(const float* __restrict__ v,
                                     float* __restrict__ X) {
    const float e0 = v[0] + v[7], e1 = v[1] + v[6];
    const float e2 = v[2] + v[5], e3 = v[3] + v[4];
    const float o0 = v[0] - v[7], o1 = v[1] - v[6];
    const float o2 = v[2] - v[5], o3 = v[3] - v[4];
    const float ee0 = e0 + e3, ee1 = e1 + e2;
    const float eo0 = e0 - e3, eo1 = e1 - e2;
    X[0] = C_035 * (ee0 + ee1);
    X[4] = C_035 * (ee0 - ee1);
    X[2] = C_046 * eo0 + C_019 * eo1;
    X[6] = C_019 * eo0 - C_046 * eo1;
    X[1] = C_049 * o0 + C_041 * o1 + C_027 * o2 + C_009 * o3;
    X[3] = C_041 * o0 - C_009 * o1 - C_049 * o2 - C_027 * o3;
    X[5] = C_027 * o0 - C_049 * o1 + C_009 * o2 + C_041 * o3;
    X[7] = C_009 * o0 - C_027 * o1 + C_041 * o2 - C_049 * o3;
}

__global__ __launch_bounds__(256) void dct2d_kernel(
        const float* __restrict__ x,
        const float* __restrict__ A,   // unused: matrix is hard-coded
        float* __restrict__ out) {
    (void)A;
    __shared__ float lds[16 * 256];   // 16 KB: 16 channels x 256 block positions

    const int tid = threadIdx.x;
    const int id  = blockIdx.x * 256 + tid;   // [0, 64*128*128)
    const int n   = id >> 14;                 // / (128*128)
    const int rem = id & 16383;
    const int gi  = rem >> 7;                 // / 128
    const int gj  = rem & 127;
    const int gi0 = gi & ~1;                  // block's first tile-row

    const float* xp = x + (size_t)n * (HW * HW) + (size_t)(gi * BS) * HW + gj * BS;

    // Stage 1: row transforms. t[k][j] = sum_l block[k][l] * A[j][l]
    float t[8][8];
    #pragma unroll
    for (int k = 0; k < 8; ++k) {
        const f32x4 lo = __builtin_nontemporal_load((const f32x4*)(xp + (size_t)k * HW));
        const f32x4 hi = __builtin_nontemporal_load((const f32x4*)(xp + (size_t)k * HW + 4));
        const float v[8] = {lo.x, lo.y, lo.z, lo.w, hi.x, hi.y, hi.z, hi.w};
        dct8(v, t[k]);
    }

    // Stage 2: column transforms. X[i][j] = sum_k A[i][k] * t[k][j]
    float X[8][8];
    #pragma unroll
    for (int j = 0; j < 8; ++j) {
        float c[8];
        #pragma unroll
        for (int k = 0; k < 8; ++k) c[k] = t[k][j];
        float col[8];
        dct8(c, col);
        #pragma unroll
        for (int i = 0; i < 8; ++i) X[i][j] = col[i];
    }

    // Stage 3: store via LDS transpose, 16 channels (2 i-rows) per round.
    const int w = tid >> 6;          // wave id 0..3
    const int l = tid & 63;          // lane
    float* obase = out + (size_t)n * (64 * PLANE) + (size_t)gi0 * GW;

    #pragma unroll
    for (int r = 0; r < 4; ++r) {
        if (r) __syncthreads();
        #pragma unroll
        for (int ii = 0; ii < 2; ++ii)
            #pragma unroll
            for (int j = 0; j < 8; ++j)
                lds[(ii * 8 + j) * 256 + tid] = X[2 * r + ii][j];
        __syncthreads();
        #pragma unroll
        for (int s = 0; s < 4; ++s) {
            const int ch_local = 4 * s + w;            // 0..15
            const int ch = r * 16 + ch_local;          // 0..63
            const f32x4 v = *(const f32x4*)&lds[ch_local * 256 + 4 * l];
            __builtin_nontemporal_store(v, (f32x4*)(obase + (size_t)ch * PLANE + 4 * l));
        }
    }
}

extern "C" void kernel_launch(void* const* d_in, const int* in_sizes, int n_in,
                              void* d_out, int out_size, void* d_ws, size_t ws_size,
                              hipStream_t stream) {
    const float* x = (const float*)d_in[0];
    const float* A = (const float*)d_in[1];
    float* out     = (float*)d_out;

    const int total_threads = NIMG * GH * GW;       // 1,048,576
    const int block = 256;
    const int grid  = total_threads / block;        // 4096 (exact)
    dct2d_kernel<<<grid, block, 0, stream>>>(x, A, out);
}